// Round 12
// baseline (673.144 us; speedup 1.0000x reference)
//
#include <hip/hip_runtime.h>
#include <math.h>

#define N_NODES 2048
#define HID 64
#define BATCH 8
#define SEQ 32
#define CAP 64           // ELL slots per row (nnz/row ~33, max ~55); zero-filled to CAP
#define TB 256           // SEQ*BATCH
#define NH (N_NODES*HID) // 131072 per batch
#define WS2 72           // fp16 W/diff row stride (halves), 16B-aligned
#define CSA2 132         // f32 C stride (words), even -> b128-aligned stores
#define CSB2 68

typedef __attribute__((ext_vector_type(8))) _Float16 half8;
typedef __attribute__((ext_vector_type(2))) _Float16 half2f;
typedef __attribute__((ext_vector_type(8))) _Float16 f16x8;
typedef __attribute__((ext_vector_type(4))) float f32x4;

__device__ __forceinline__ float fast_sig(float s) {
  return 1.f / (1.f + __expf(-s));
}
__device__ __forceinline__ float fast_tanh(float s) {
  float e = __expf(-2.f * fabsf(s));
  float t = 1.f - 2.f * e / (1.f + e);
  return copysignf(t, s);
}

// ---------------- Kernel 0: build ELL, zero-filled through CAP --------------
__global__ __launch_bounds__(256) void k_build_ell(
    const float* __restrict__ L, float* __restrict__ ell_val,
    _Float16* __restrict__ ell_valh, int* __restrict__ ell_colh,
    int* __restrict__ ell_cnt) {
  int wave = (blockIdx.x * blockDim.x + threadIdx.x) >> 6;
  int lane = threadIdx.x & 63;
  if (wave >= N_NODES) return;
  const float* row = L + (size_t)wave * N_NODES;
  int base = 0;
  for (int c = 0; c < N_NODES / 64; ++c) {
    int col = c * 64 + lane;
    float v = row[col];
    bool nz = (v != 0.0f);
    unsigned long long mask = __ballot(nz);
    int before = __popcll(mask & ((1ull << lane) - 1ull));
    if (nz) {
      int slot = base + before;
      if (slot < CAP) {
        ell_colh[wave * CAP + slot] = col * HID;
        ell_val[wave * CAP + slot] = v;
        ell_valh[wave * CAP + slot] = (_Float16)v;
      }
    }
    base += __popcll(mask);
  }
  if (base > CAP) base = CAP;
  for (int s = base + lane; s < CAP; s += 64) {
    ell_colh[wave * CAP + s] = 0;
    ell_val[wave * CAP + s] = 0.f;
    ell_valh[wave * CAP + s] = (_Float16)0.f;
  }
  int pad = (base + 7) & ~7;
  if (pad > CAP) pad = CAP;
  if (lane == 0) ell_cnt[wave] = pad;
}

// ---------------- Sort rows by padded cnt (stable, deterministic) -----------
__global__ __launch_bounds__(64) void k_sort(const int* __restrict__ ell_cnt,
                                             int* __restrict__ rowmap) {
  int lane = threadIdx.x;
  int h[9];
  #pragma unroll
  for (int j = 0; j < 9; ++j) h[j] = 0;
  for (int c = 0; c < N_NODES / 64; ++c) {
    int v = ell_cnt[c * 64 + lane] >> 3;
    #pragma unroll
    for (int j = 0; j < 9; ++j) h[j] += __popcll(__ballot(v == j));
  }
  int cur[9];
  int run = 0;
  #pragma unroll
  for (int j = 0; j < 9; ++j) { cur[j] = run; run += h[j]; }
  for (int c = 0; c < N_NODES / 64; ++c) {
    int v = ell_cnt[c * 64 + lane] >> 3;
    #pragma unroll
    for (int j = 0; j < 9; ++j) {
      unsigned long long mask = __ballot(v == j);
      int before = __popcll(mask & ((1ull << lane) - 1ull));
      if (v == j) rowmap[cur[j] + before] = c * 64 + lane;
      cur[j] += __popcll(mask);
    }
  }
}

// ---------------- Prolog: pre-swizzled fp16 W images + wx arrays ------------
__global__ __launch_bounds__(256) void k_prep(
    const float* __restrict__ Wg, const float* __restrict__ Wc,
    _Float16* __restrict__ Wg16, _Float16* __restrict__ Wc16,
    float* __restrict__ wgx, float* __restrict__ wcx) {
  int tid = blockIdx.x * blockDim.x + threadIdx.x;
  int nthr = gridDim.x * blockDim.x;
  for (int i = tid; i < 128 * WS2; i += nthr) {
    int o = i / WS2, h = i % WS2;
    Wg16[i] = (h < 64) ? (_Float16)Wg[o * 65 + 1 + h] : (_Float16)0.f;
  }
  for (int i = tid; i < 64 * WS2; i += nthr) {
    int o = i / WS2, h = i % WS2;
    Wc16[i] = (h < 64) ? (_Float16)Wc[o * 65 + 1 + h] : (_Float16)0.f;
  }
  if (tid < 128) wgx[tid] = Wg[tid * 65];
  else if (tid < 192) wcx[tid - 128] = Wc[(tid - 128) * 65];
}

// ---------------- Transpose x[b][t][n] -> xT[n][tb],  tb = t*8 + b ----------
__global__ __launch_bounds__(256) void k_xt(const float* __restrict__ x,
                                            float* __restrict__ xT) {
  __shared__ float s[32][65];
  int n0  = (blockIdx.x & 63) * 32;
  int tb0 = (blockIdx.x >> 6) * 64;
  for (int idx = threadIdx.x; idx < 32 * 64; idx += 256) {
    int ln = idx & 31, ltb = idx >> 5;
    int tb = tb0 + ltb; int b = tb & 7, t = tb >> 3;
    s[ln][ltb] = x[((size_t)b * SEQ + t) * N_NODES + n0 + ln];
  }
  __syncthreads();
  for (int idx = threadIdx.x; idx < 32 * 64; idx += 256) {
    int ln = idx >> 6, ltb = idx & 63;
    xT[(size_t)(n0 + ln) * TB + tb0 + ltb] = s[ln][ltb];
  }
}

// ---------------- LxT[m][tb] = sum_n L[m,n] * xT[n][tb] ---------------------
__global__ __launch_bounds__(512) void k_spmm_x(
    const float* __restrict__ xT, const float* __restrict__ ell_val,
    const int* __restrict__ ell_colh, const int* __restrict__ ell_cnt,
    float* __restrict__ LxT) {
  int m = (blockIdx.x * blockDim.x + threadIdx.x) >> 6;
  int lane = threadIdx.x & 63;
  if (m >= N_NODES) return;
  const int* cp = ell_colh + m * CAP;
  const float* vp = ell_val + m * CAP;
  int cnt = ell_cnt[m];
  float4 acc = {0.f, 0.f, 0.f, 0.f};
  for (int k = 0; k < cnt; k += 4) {
    int4 c = *(const int4*)(cp + k);
    float4 v = *(const float4*)(vp + k);
    float4 xa = *(const float4*)&xT[(size_t)c.x * 4 + lane * 4];
    float4 xb = *(const float4*)&xT[(size_t)c.y * 4 + lane * 4];
    float4 xc = *(const float4*)&xT[(size_t)c.z * 4 + lane * 4];
    float4 xd = *(const float4*)&xT[(size_t)c.w * 4 + lane * 4];
    acc.x = fmaf(v.x, xa.x, acc.x); acc.y = fmaf(v.x, xa.y, acc.y);
    acc.z = fmaf(v.x, xa.z, acc.z); acc.w = fmaf(v.x, xa.w, acc.w);
    acc.x = fmaf(v.y, xb.x, acc.x); acc.y = fmaf(v.y, xb.y, acc.y);
    acc.z = fmaf(v.y, xb.z, acc.z); acc.w = fmaf(v.y, xb.w, acc.w);
    acc.x = fmaf(v.z, xc.x, acc.x); acc.y = fmaf(v.z, xc.y, acc.y);
    acc.z = fmaf(v.z, xc.z, acc.z); acc.w = fmaf(v.z, xc.w, acc.w);
    acc.x = fmaf(v.w, xd.x, acc.x); acc.y = fmaf(v.w, xd.y, acc.y);
    acc.z = fmaf(v.w, xd.z, acc.z); acc.w = fmaf(v.w, xd.w, acc.w);
  }
  *(float4*)&LxT[(size_t)m * TB + lane * 4] = acc;
}

// ---------------- Kernel 1: gates — 1 wave = 2 sorted nodes, no barriers ----
__global__ __launch_bounds__(64) void k_gates(
    const half8* __restrict__ statepk, const float* __restrict__ LxT,
    const _Float16* __restrict__ ell_valh, const int* __restrict__ ell_colh,
    const int* __restrict__ ell_cnt, const _Float16* __restrict__ Wg16,
    const float* __restrict__ wgx, const float* __restrict__ bg,
    half8* __restrict__ rspk, half8* __restrict__ upk,
    const int* __restrict__ rowmap, int t) {
  __shared__ __align__(16) _Float16 sdiff[16 * WS2];
  __shared__ __align__(16) float sC[16 * CSA2];
  int lane = threadIdx.x;
  int mA = rowmap[blockIdx.x * 2];
  int mB = rowmap[blockIdx.x * 2 + 1];
  const half8* pk = statepk + lane;
  const int* cpA = ell_colh + mA * CAP;
  const _Float16* vpA = ell_valh + mA * CAP;
  const int* cpB = ell_colh + mB * CAP;
  const _Float16* vpB = ell_valh + mB * CAP;
  int cA = ell_cnt[mA], cB = ell_cnt[mB];
  int cnt = (cA > cB) ? cA : cB;           // zero-filled slots make overrun safe
  half2f aA01={0,0},aA23={0,0},aA45={0,0},aA67={0,0};
  half2f aB01={0,0},aB23={0,0},aB45={0,0},aB67={0,0};
  for (int k = 0; k < cnt; k += 8) {
    int4 caA = *(const int4*)(cpA + k);
    int4 cbA = *(const int4*)(cpA + k + 4);
    half8 vvA = *(const half8*)(vpA + k);
    int4 caB = *(const int4*)(cpB + k);
    int4 cbB = *(const int4*)(cpB + k + 4);
    half8 vvB = *(const half8*)(vpB + k);
#define GA(C, V) { half8 hv = pk[C]; const half2f* h2 = (const half2f*)&hv; \
    half2f vs = {V, V}; aA01 += vs*h2[0]; aA23 += vs*h2[1]; \
    aA45 += vs*h2[2]; aA67 += vs*h2[3]; }
#define GB(C, V) { half8 hv = pk[C]; const half2f* h2 = (const half2f*)&hv; \
    half2f vs = {V, V}; aB01 += vs*h2[0]; aB23 += vs*h2[1]; \
    aB45 += vs*h2[2]; aB67 += vs*h2[3]; }
    GA(caA.x, vvA[0]) GB(caB.x, vvB[0]) GA(caA.y, vvA[1]) GB(caB.y, vvB[1])
    GA(caA.z, vvA[2]) GB(caB.z, vvB[2]) GA(caA.w, vvA[3]) GB(caB.w, vvB[3])
    GA(cbA.x, vvA[4]) GB(cbB.x, vvB[4]) GA(cbA.y, vvA[5]) GB(cbB.y, vvB[5])
    GA(cbA.z, vvA[6]) GB(cbB.z, vvB[6]) GA(cbA.w, vvA[7]) GB(cbB.w, vvB[7])
#undef GA
#undef GB
  }
  // rows 0..7 = node A (b=0..7), rows 8..15 = node B; wave-private LDS
  sdiff[ 0*WS2+lane]=aA01[0]; sdiff[ 1*WS2+lane]=aA01[1];
  sdiff[ 2*WS2+lane]=aA23[0]; sdiff[ 3*WS2+lane]=aA23[1];
  sdiff[ 4*WS2+lane]=aA45[0]; sdiff[ 5*WS2+lane]=aA45[1];
  sdiff[ 6*WS2+lane]=aA67[0]; sdiff[ 7*WS2+lane]=aA67[1];
  sdiff[ 8*WS2+lane]=aB01[0]; sdiff[ 9*WS2+lane]=aB01[1];
  sdiff[10*WS2+lane]=aB23[0]; sdiff[11*WS2+lane]=aB23[1];
  sdiff[12*WS2+lane]=aB45[0]; sdiff[13*WS2+lane]=aB45[1];
  sdiff[14*WS2+lane]=aB67[0]; sdiff[15*WS2+lane]=aB67[1];
  int l15 = lane & 15, lq = lane >> 4;
  f16x8 bf0 = *(const f16x8*)&sdiff[l15 * WS2 + 0 * 32 + lq * 8];
  f16x8 bf1 = *(const f16x8*)&sdiff[l15 * WS2 + 1 * 32 + lq * 8];
  #pragma unroll
  for (int ot = 0; ot < 8; ++ot) {
    f32x4 acc = {0.f, 0.f, 0.f, 0.f};
    f16x8 af0 = *(const f16x8*)&Wg16[(ot * 16 + l15) * WS2 + 0 * 32 + lq * 8];
    f16x8 af1 = *(const f16x8*)&Wg16[(ot * 16 + l15) * WS2 + 1 * 32 + lq * 8];
    acc = __builtin_amdgcn_mfma_f32_16x16x32_f16(af0, bf0, acc, 0, 0, 0);
    acc = __builtin_amdgcn_mfma_f32_16x16x32_f16(af1, bf1, acc, 0, 0, 0);
    *(f32x4*)&sC[l15 * CSA2 + ot * 16 + lq * 4] = acc;
  }
  int o0 = lane, o1 = lane + 64;
  float wx0 = wgx[o0], bg0 = bg[o0];
  float wx1 = wgx[o1], bg1 = bg[o1];
  int mm[2] = {mA, mB};
  #pragma unroll
  for (int nn = 0; nn < 2; ++nn) {
    int m = mm[nn];
    float4 LxLo = *(const float4*)&LxT[(size_t)m * TB + t * BATCH];
    float4 LxHi = *(const float4*)&LxT[(size_t)m * TB + t * BATCH + 4];
    float Lx8[8] = {LxLo.x, LxLo.y, LxLo.z, LxLo.w,
                    LxHi.x, LxHi.y, LxHi.z, LxHi.w};
    float s0[8], s1[8];
    #pragma unroll
    for (int b = 0; b < 8; ++b) {
      int R = nn * 8 + b;
      s0[b] = sC[R * CSA2 + o0] + fmaf(Lx8[b], wx0, bg0);
      s1[b] = sC[R * CSA2 + o1] + fmaf(Lx8[b], wx1, bg1);
    }
    if (m < N_NODES / 2) {
      // r-half: flat gate idx == flat state idx (rep0 -> node 2m, rep1 -> 2m+1)
      half8 sp0 = pk[m * 128];
      half8 sp1 = pk[m * 128 + 64];
      half8 r0, r1;
      #pragma unroll
      for (int b = 0; b < 8; ++b) {
        r0[b] = (_Float16)(fast_sig(s0[b]) * (float)sp0[b]);
        r1[b] = (_Float16)(fast_sig(s1[b]) * (float)sp1[b]);
      }
      half8* rp = rspk + lane;
      rp[m * 128] = r0;
      rp[m * 128 + 64] = r1;
    } else {
      int mq = m - N_NODES / 2;
      half8 u0, u1;
      #pragma unroll
      for (int b = 0; b < 8; ++b) {
        u0[b] = (_Float16)fast_sig(s0[b]);
        u1[b] = (_Float16)fast_sig(s1[b]);
      }
      half8* up2 = upk + lane;
      up2[mq * 128] = u0;
      up2[mq * 128 + 64] = u1;
    }
  }
}

// ---------------- Kernel 2: cand + GRU — 1 wave = 2 sorted nodes ------------
__global__ __launch_bounds__(64) void k_cand(
    const half8* __restrict__ statepk, const float* __restrict__ LxT,
    const _Float16* __restrict__ ell_valh, const int* __restrict__ ell_colh,
    const int* __restrict__ ell_cnt, const _Float16* __restrict__ Wc16,
    const float* __restrict__ wcx, const float* __restrict__ bc,
    const half8* __restrict__ rspk, const half8* __restrict__ upk,
    half8* __restrict__ statepk_next, float* __restrict__ out,
    const int* __restrict__ rowmap, int t) {
  __shared__ __align__(16) _Float16 sdiff[16 * WS2];
  __shared__ __align__(16) float sC[16 * CSB2];
  int lane = threadIdx.x;
  int mA = rowmap[blockIdx.x * 2];
  int mB = rowmap[blockIdx.x * 2 + 1];
  const half8* rk = rspk + lane;
  const int* cpA = ell_colh + mA * CAP;
  const _Float16* vpA = ell_valh + mA * CAP;
  const int* cpB = ell_colh + mB * CAP;
  const _Float16* vpB = ell_valh + mB * CAP;
  int cA = ell_cnt[mA], cB = ell_cnt[mB];
  int cnt = (cA > cB) ? cA : cB;
  half2f aA01={0,0},aA23={0,0},aA45={0,0},aA67={0,0};
  half2f aB01={0,0},aB23={0,0},aB45={0,0},aB67={0,0};
  for (int k = 0; k < cnt; k += 8) {
    int4 caA = *(const int4*)(cpA + k);
    int4 cbA = *(const int4*)(cpA + k + 4);
    half8 vvA = *(const half8*)(vpA + k);
    int4 caB = *(const int4*)(cpB + k);
    int4 cbB = *(const int4*)(cpB + k + 4);
    half8 vvB = *(const half8*)(vpB + k);
#define GA(C, V) { half8 hv = rk[C]; const half2f* h2 = (const half2f*)&hv; \
    half2f vs = {V, V}; aA01 += vs*h2[0]; aA23 += vs*h2[1]; \
    aA45 += vs*h2[2]; aA67 += vs*h2[3]; }
#define GB(C, V) { half8 hv = rk[C]; const half2f* h2 = (const half2f*)&hv; \
    half2f vs = {V, V}; aB01 += vs*h2[0]; aB23 += vs*h2[1]; \
    aB45 += vs*h2[2]; aB67 += vs*h2[3]; }
    GA(caA.x, vvA[0]) GB(caB.x, vvB[0]) GA(caA.y, vvA[1]) GB(caB.y, vvB[1])
    GA(caA.z, vvA[2]) GB(caB.z, vvB[2]) GA(caA.w, vvA[3]) GB(caB.w, vvB[3])
    GA(cbA.x, vvA[4]) GB(cbB.x, vvB[4]) GA(cbA.y, vvA[5]) GB(cbB.y, vvB[5])
    GA(cbA.z, vvA[6]) GB(cbB.z, vvB[6]) GA(cbA.w, vvA[7]) GB(cbB.w, vvB[7])
#undef GA
#undef GB
  }
  sdiff[ 0*WS2+lane]=aA01[0]; sdiff[ 1*WS2+lane]=aA01[1];
  sdiff[ 2*WS2+lane]=aA23[0]; sdiff[ 3*WS2+lane]=aA23[1];
  sdiff[ 4*WS2+lane]=aA45[0]; sdiff[ 5*WS2+lane]=aA45[1];
  sdiff[ 6*WS2+lane]=aA67[0]; sdiff[ 7*WS2+lane]=aA67[1];
  sdiff[ 8*WS2+lane]=aB01[0]; sdiff[ 9*WS2+lane]=aB01[1];
  sdiff[10*WS2+lane]=aB23[0]; sdiff[11*WS2+lane]=aB23[1];
  sdiff[12*WS2+lane]=aB45[0]; sdiff[13*WS2+lane]=aB45[1];
  sdiff[14*WS2+lane]=aB67[0]; sdiff[15*WS2+lane]=aB67[1];
  int l15 = lane & 15, lq = lane >> 4;
  f16x8 bf0 = *(const f16x8*)&sdiff[l15 * WS2 + 0 * 32 + lq * 8];
  f16x8 bf1 = *(const f16x8*)&sdiff[l15 * WS2 + 1 * 32 + lq * 8];
  #pragma unroll
  for (int ot = 0; ot < 4; ++ot) {
    f32x4 acc = {0.f, 0.f, 0.f, 0.f};
    f16x8 af0 = *(const f16x8*)&Wc16[(ot * 16 + l15) * WS2 + 0 * 32 + lq * 8];
    f16x8 af1 = *(const f16x8*)&Wc16[(ot * 16 + l15) * WS2 + 1 * 32 + lq * 8];
    acc = __builtin_amdgcn_mfma_f32_16x16x32_f16(af0, bf0, acc, 0, 0, 0);
    acc = __builtin_amdgcn_mfma_f32_16x16x32_f16(af1, bf1, acc, 0, 0, 0);
    *(f32x4*)&sC[l15 * CSB2 + ot * 16 + lq * 4] = acc;
  }
  float wxc = wcx[lane], bbc = bc[lane];
  int mm[2] = {mA, mB};
  #pragma unroll
  for (int nn = 0; nn < 2; ++nn) {
    int m = mm[nn];
    float4 LxLo = *(const float4*)&LxT[(size_t)m * TB + t * BATCH];
    float4 LxHi = *(const float4*)&LxT[(size_t)m * TB + t * BATCH + 4];
    float Lx8[8] = {LxLo.x, LxLo.y, LxLo.z, LxLo.w,
                    LxHi.x, LxHi.y, LxHi.z, LxHi.w};
    float s[8];
    #pragma unroll
    for (int b = 0; b < 8; ++b) {
      int R = nn * 8 + b;
      s[b] = sC[R * CSB2 + lane] + fmaf(Lx8[b], wxc, bbc);
    }
    half8 hp = (statepk + lane)[m * 64];
    half8 uu = (upk + lane)[m * 64];
    half8 np;
    float* op = out + (size_t)t * BATCH * NH + m * HID + lane;
    #pragma unroll
    for (int b = 0; b < 8; ++b) {
      float u = (float)uu[b];
      float nh = u * (float)hp[b] + (1.f - u) * fast_tanh(s[b]);
      np[b] = (_Float16)nh;
      op[(size_t)b * NH] = nh;
    }
    (statepk_next + lane)[m * 64] = np;
  }
}

extern "C" void kernel_launch(void* const* d_in, const int* in_sizes, int n_in,
                              void* d_out, int out_size, void* d_ws, size_t ws_size,
                              hipStream_t stream) {
  const float* x  = (const float*)d_in[0];
  const float* L  = (const float*)d_in[1];
  const float* Wg = (const float*)d_in[2];
  const float* bg = (const float*)d_in[3];
  const float* Wc = (const float*)d_in[4];
  const float* bc = (const float*)d_in[5];
  float* out = (float*)d_out;
  float* ws = (float*)d_ws;

  float*    ell_val  = ws;                                      // N*CAP f32
  int*      ell_colh = (int*)(ws + (size_t)N_NODES * CAP);      // N*CAP i32
  _Float16* ell_valh = (_Float16*)(ws + (size_t)2 * N_NODES * CAP); // N*CAP f16
  int*      ell_cnt  = (int*)(ws + (size_t)2 * N_NODES * CAP + N_NODES * CAP / 2); // N
  float* xT  = ws + (size_t)2 * N_NODES * CAP + N_NODES * CAP / 2 + N_NODES;
  float* LxT = xT + (size_t)N_NODES * TB;
  float* fend = LxT + (size_t)N_NODES * TB;
  half8* stA  = (half8*)fend;                                   // N*64 half8 = 2MB
  half8* stB  = stA + (size_t)N_NODES * HID;
  half8* rspk = stB + (size_t)N_NODES * HID;
  half8* upk  = rspk + (size_t)N_NODES * HID;
  _Float16* Wg16 = (_Float16*)(upk + (size_t)N_NODES * HID);    // 128*72 halves
  _Float16* Wc16 = Wg16 + 128 * WS2;                            // 64*72 halves
  float* wgx = (float*)(Wc16 + 64 * WS2);                       // 128 f32
  float* wcx = wgx + 128;                                       // 64 f32
  int* rowmap = (int*)(wcx + 64);                               // N i32

  k_build_ell<<<N_NODES / 4, 256, 0, stream>>>(L, ell_val, ell_valh, ell_colh,
                                               ell_cnt);
  k_sort<<<1, 64, 0, stream>>>(ell_cnt, rowmap);
  k_prep<<<64, 256, 0, stream>>>(Wg, Wc, Wg16, Wc16, wgx, wcx);
  k_xt<<<256, 256, 0, stream>>>(x, xT);
  k_spmm_x<<<N_NODES / 8, 512, 0, stream>>>(xT, ell_val, ell_colh, ell_cnt, LxT);
  hipMemsetAsync(stA, 0, (size_t)N_NODES * HID * sizeof(half8), stream);

  half8* cur = stA;
  half8* nxt = stB;
  for (int t = 0; t < SEQ; ++t) {
    k_gates<<<N_NODES / 2, 64, 0, stream>>>(cur, LxT, ell_valh, ell_colh,
                                            ell_cnt, Wg16, wgx, bg, rspk, upk,
                                            rowmap, t);
    k_cand<<<N_NODES / 2, 64, 0, stream>>>(cur, LxT, ell_valh, ell_colh,
                                           ell_cnt, Wc16, wcx, bc, rspk, upk,
                                           nxt, out, rowmap, t);
    half8* tmp = cur; cur = nxt; nxt = tmp;
  }
}

// Round 13
// 650.808 us; speedup vs baseline: 1.0343x; 1.0343x over previous
//
#include <hip/hip_runtime.h>
#include <math.h>

#define N_NODES 2048
#define HID 64
#define BATCH 8
#define SEQ 32
#define CAP 64           // ELL slots per row (nnz/row ~33, max ~55, padded x8)
#define TB 256           // SEQ*BATCH
#define NH (N_NODES*HID) // 131072 per batch
#define WS2 72           // fp16 W image row stride (halves), 16B-aligned
#define CSA2 132         // f32 C stride (words): even->b128-aligned, 2-way read banks
#define CSB2 68

typedef __attribute__((ext_vector_type(8))) _Float16 half8;
typedef __attribute__((ext_vector_type(2))) _Float16 half2f;
typedef __attribute__((ext_vector_type(8))) _Float16 f16x8;
typedef __attribute__((ext_vector_type(4))) float f32x4;

__device__ __forceinline__ float fast_sig(float s) {
  return 1.f / (1.f + __expf(-s));
}
__device__ __forceinline__ float fast_tanh(float s) {
  float e = __expf(-2.f * fabsf(s));
  float t = 1.f - 2.f * e / (1.f + e);
  return copysignf(t, s);
}

// ---------------- Kernel 0: build padded ELL (colh = col*HID) ---------------
__global__ __launch_bounds__(256) void k_build_ell(
    const float* __restrict__ L, float* __restrict__ ell_val,
    _Float16* __restrict__ ell_valh, int* __restrict__ ell_colh,
    int* __restrict__ ell_cnt) {
  int wave = (blockIdx.x * blockDim.x + threadIdx.x) >> 6;
  int lane = threadIdx.x & 63;
  if (wave >= N_NODES) return;
  const float* row = L + (size_t)wave * N_NODES;
  int base = 0;
  for (int c = 0; c < N_NODES / 64; ++c) {
    int col = c * 64 + lane;
    float v = row[col];
    bool nz = (v != 0.0f);
    unsigned long long mask = __ballot(nz);
    int before = __popcll(mask & ((1ull << lane) - 1ull));
    if (nz) {
      int slot = base + before;
      if (slot < CAP) {
        ell_colh[wave * CAP + slot] = col * HID;
        ell_val[wave * CAP + slot] = v;
        ell_valh[wave * CAP + slot] = (_Float16)v;
      }
    }
    base += __popcll(mask);
  }
  if (base > CAP) base = CAP;
  int pad = (base + 7) & ~7;
  if (pad > CAP) pad = CAP;
  for (int s = base + lane; s < pad; s += 64) {
    ell_colh[wave * CAP + s] = 0;
    ell_val[wave * CAP + s] = 0.f;
    ell_valh[wave * CAP + s] = (_Float16)0.f;
  }
  if (lane == 0) ell_cnt[wave] = pad;
}

// ---------------- Prolog: pre-swizzled fp16 W images + wx arrays ------------
__global__ __launch_bounds__(256) void k_prep(
    const float* __restrict__ Wg, const float* __restrict__ Wc,
    _Float16* __restrict__ Wg16, _Float16* __restrict__ Wc16,
    float* __restrict__ wgx, float* __restrict__ wcx) {
  int tid = blockIdx.x * blockDim.x + threadIdx.x;
  int nthr = gridDim.x * blockDim.x;
  for (int i = tid; i < 128 * WS2; i += nthr) {
    int o = i / WS2, h = i % WS2;
    Wg16[i] = (h < 64) ? (_Float16)Wg[o * 65 + 1 + h] : (_Float16)0.f;
  }
  for (int i = tid; i < 64 * WS2; i += nthr) {
    int o = i / WS2, h = i % WS2;
    Wc16[i] = (h < 64) ? (_Float16)Wc[o * 65 + 1 + h] : (_Float16)0.f;
  }
  if (tid < 128) wgx[tid] = Wg[tid * 65];
  else if (tid < 192) wcx[tid - 128] = Wc[(tid - 128) * 65];
}

// ---------------- Transpose x[b][t][n] -> xT[n][tb],  tb = t*8 + b ----------
__global__ __launch_bounds__(256) void k_xt(const float* __restrict__ x,
                                            float* __restrict__ xT) {
  __shared__ float s[32][65];
  int n0  = (blockIdx.x & 63) * 32;
  int tb0 = (blockIdx.x >> 6) * 64;
  for (int idx = threadIdx.x; idx < 32 * 64; idx += 256) {
    int ln = idx & 31, ltb = idx >> 5;
    int tb = tb0 + ltb; int b = tb & 7, t = tb >> 3;
    s[ln][ltb] = x[((size_t)b * SEQ + t) * N_NODES + n0 + ln];
  }
  __syncthreads();
  for (int idx = threadIdx.x; idx < 32 * 64; idx += 256) {
    int ln = idx >> 6, ltb = idx & 63;
    xT[(size_t)(n0 + ln) * TB + tb0 + ltb] = s[ln][ltb];
  }
}

// ---------------- LxT[m][tb] = sum_n L[m,n] * xT[n][tb] ---------------------
__global__ __launch_bounds__(512) void k_spmm_x(
    const float* __restrict__ xT, const float* __restrict__ ell_val,
    const int* __restrict__ ell_colh, const int* __restrict__ ell_cnt,
    float* __restrict__ LxT) {
  int m = (blockIdx.x * blockDim.x + threadIdx.x) >> 6;
  int lane = threadIdx.x & 63;
  if (m >= N_NODES) return;
  const int* cp = ell_colh + m * CAP;
  const float* vp = ell_val + m * CAP;
  int cnt = ell_cnt[m];
  float4 acc = {0.f, 0.f, 0.f, 0.f};
  for (int k = 0; k < cnt; k += 4) {
    int4 c = *(const int4*)(cp + k);
    float4 v = *(const float4*)(vp + k);
    float4 xa = *(const float4*)&xT[(size_t)c.x * 4 + lane * 4];
    float4 xb = *(const float4*)&xT[(size_t)c.y * 4 + lane * 4];
    float4 xc = *(const float4*)&xT[(size_t)c.z * 4 + lane * 4];
    float4 xd = *(const float4*)&xT[(size_t)c.w * 4 + lane * 4];
    acc.x = fmaf(v.x, xa.x, acc.x); acc.y = fmaf(v.x, xa.y, acc.y);
    acc.z = fmaf(v.x, xa.z, acc.z); acc.w = fmaf(v.x, xa.w, acc.w);
    acc.x = fmaf(v.y, xb.x, acc.x); acc.y = fmaf(v.y, xb.y, acc.y);
    acc.z = fmaf(v.y, xb.z, acc.z); acc.w = fmaf(v.y, xb.w, acc.w);
    acc.x = fmaf(v.z, xc.x, acc.x); acc.y = fmaf(v.z, xc.y, acc.y);
    acc.z = fmaf(v.z, xc.z, acc.z); acc.w = fmaf(v.z, xc.w, acc.w);
    acc.x = fmaf(v.w, xd.x, acc.x); acc.y = fmaf(v.w, xd.y, acc.y);
    acc.z = fmaf(v.w, xd.z, acc.z); acc.w = fmaf(v.w, xd.w, acc.w);
  }
  *(float4*)&LxT[(size_t)m * TB + lane * 4] = acc;
}

// ---------------- Kernel 1: gates (fp16 gather + MFMA, W from global) -------
__global__ __launch_bounds__(256, 4) void k_gates(
    const half8* __restrict__ statepk, const float* __restrict__ LxT,
    const _Float16* __restrict__ ell_valh, const int* __restrict__ ell_colh,
    const int* __restrict__ ell_cnt, const _Float16* __restrict__ Wg16,
    const float* __restrict__ wgx, const float* __restrict__ bg,
    half8* __restrict__ rspk, half8* __restrict__ upk, int t) {
  __shared__ __align__(16) _Float16 sdiff[32 * WS2];
  __shared__ __align__(16) float sC[32 * CSA2];
  int wv = threadIdx.x >> 6, lane = threadIdx.x & 63;
  int m = blockIdx.x * 4 + wv;
  const half8* pk = statepk + lane;
  const int* cp = ell_colh + m * CAP;
  const _Float16* vp = ell_valh + m * CAP;
  int cnt = ell_cnt[m];
  int l15 = lane & 15, lq = lane >> 4;
  // prefetch A-fragments (L2-hot, hidden behind gather)
  f16x8 afrag[2][2];
  {
    int ot0 = wv * 2;
    #pragma unroll
    for (int oo = 0; oo < 2; ++oo)
      #pragma unroll
      for (int s = 0; s < 2; ++s)
        afrag[oo][s] = *(const f16x8*)&Wg16[((ot0 + oo) * 16 + l15) * WS2 +
                                            s * 32 + lq * 8];
  }
  half2f a01 = {0, 0}, a23 = {0, 0}, a45 = {0, 0}, a67 = {0, 0};
  for (int k = 0; k < cnt; k += 8) {
    int4 ca = *(const int4*)(cp + k);
    int4 cb = *(const int4*)(cp + k + 4);
    half8 vv = *(const half8*)(vp + k);
#define GATH(C, V) { half8 hv = pk[C]; \
    const half2f* h2 = (const half2f*)&hv; \
    half2f vs = {V, V}; \
    a01 += vs * h2[0]; a23 += vs * h2[1]; \
    a45 += vs * h2[2]; a67 += vs * h2[3]; }
    GATH(ca.x, vv[0]) GATH(ca.y, vv[1]) GATH(ca.z, vv[2]) GATH(ca.w, vv[3])
    GATH(cb.x, vv[4]) GATH(cb.y, vv[5]) GATH(cb.z, vv[6]) GATH(cb.w, vv[7])
#undef GATH
  }
  {
    int r0 = wv * 8;
    sdiff[(r0 + 0) * WS2 + lane] = a01[0];
    sdiff[(r0 + 1) * WS2 + lane] = a01[1];
    sdiff[(r0 + 2) * WS2 + lane] = a23[0];
    sdiff[(r0 + 3) * WS2 + lane] = a23[1];
    sdiff[(r0 + 4) * WS2 + lane] = a45[0];
    sdiff[(r0 + 5) * WS2 + lane] = a45[1];
    sdiff[(r0 + 6) * WS2 + lane] = a67[0];
    sdiff[(r0 + 7) * WS2 + lane] = a67[1];
  }
  __syncthreads();
  #pragma unroll
  for (int tt = 0; tt < 4; ++tt) {
    int tid = wv * 4 + tt;
    int ot = tid >> 1, rt = tid & 1;
    f32x4 acc = {0.f, 0.f, 0.f, 0.f};
    #pragma unroll
    for (int s = 0; s < 2; ++s) {
      f16x8 bf = *(const f16x8*)&sdiff[(rt * 16 + l15) * WS2 + s * 32 + lq * 8];
      acc = __builtin_amdgcn_mfma_f32_16x16x32_f16(afrag[tt >> 1][s], bf, acc,
                                                   0, 0, 0);
    }
    int R = rt * 16 + l15;
    int O = ot * 16 + lq * 4;
    *(f32x4*)&sC[R * CSA2 + O] = acc;
  }
  __syncthreads();
  float4 LxLo = *(const float4*)&LxT[(size_t)m * TB + t * BATCH];
  float4 LxHi = *(const float4*)&LxT[(size_t)m * TB + t * BATCH + 4];
  float Lx8[8] = {LxLo.x, LxLo.y, LxLo.z, LxLo.w,
                  LxHi.x, LxHi.y, LxHi.z, LxHi.w};
  int o0 = lane, o1 = lane + 64;
  float wx0 = wgx[o0], bg0 = bg[o0];
  float wx1 = wgx[o1], bg1 = bg[o1];
  float s0[8], s1[8];
  #pragma unroll
  for (int b = 0; b < 8; ++b) {
    int R = wv * 8 + b;
    s0[b] = sC[R * CSA2 + o0] + fmaf(Lx8[b], wx0, bg0);
    s1[b] = sC[R * CSA2 + o1] + fmaf(Lx8[b], wx1, bg1);
  }
  if (m < N_NODES / 2) {
    // r-half: flat gate idx == flat state idx (rep0 -> node 2m, rep1 -> 2m+1)
    half8 sp0 = pk[m * 128];
    half8 sp1 = pk[m * 128 + 64];
    half8 r0, r1;
    #pragma unroll
    for (int b = 0; b < 8; ++b) {
      r0[b] = (_Float16)(fast_sig(s0[b]) * (float)sp0[b]);
      r1[b] = (_Float16)(fast_sig(s1[b]) * (float)sp1[b]);
    }
    half8* rp = rspk + lane;
    rp[m * 128] = r0;
    rp[m * 128 + 64] = r1;
  } else {
    int mm = m - N_NODES / 2;
    half8 u0, u1;
    #pragma unroll
    for (int b = 0; b < 8; ++b) {
      u0[b] = (_Float16)fast_sig(s0[b]);
      u1[b] = (_Float16)fast_sig(s1[b]);
    }
    half8* up2 = upk + lane;
    up2[mm * 128] = u0;
    up2[mm * 128 + 64] = u1;
  }
}

// ---------------- Kernel 2: cand + GRU update (W from global) ---------------
__global__ __launch_bounds__(256, 4) void k_cand(
    const half8* __restrict__ statepk, const float* __restrict__ LxT,
    const _Float16* __restrict__ ell_valh, const int* __restrict__ ell_colh,
    const int* __restrict__ ell_cnt, const _Float16* __restrict__ Wc16,
    const float* __restrict__ wcx, const float* __restrict__ bc,
    const half8* __restrict__ rspk, const half8* __restrict__ upk,
    half8* __restrict__ statepk_next, float* __restrict__ out, int t) {
  __shared__ __align__(16) _Float16 sdiff[32 * WS2];
  __shared__ __align__(16) float sC[32 * CSB2];
  int wv = threadIdx.x >> 6, lane = threadIdx.x & 63;
  int m = blockIdx.x * 4 + wv;
  const half8* rk = rspk + lane;
  const int* cp = ell_colh + m * CAP;
  const _Float16* vp = ell_valh + m * CAP;
  int cnt = ell_cnt[m];
  int l15 = lane & 15, lq = lane >> 4;
  f16x8 afrag[2];
  #pragma unroll
  for (int s = 0; s < 2; ++s)
    afrag[s] = *(const f16x8*)&Wc16[(wv * 16 + l15) * WS2 + s * 32 + lq * 8];
  half2f a01 = {0, 0}, a23 = {0, 0}, a45 = {0, 0}, a67 = {0, 0};
  for (int k = 0; k < cnt; k += 8) {
    int4 ca = *(const int4*)(cp + k);
    int4 cb = *(const int4*)(cp + k + 4);
    half8 vv = *(const half8*)(vp + k);
#define GATH(C, V) { half8 hv = rk[C]; \
    const half2f* h2 = (const half2f*)&hv; \
    half2f vs = {V, V}; \
    a01 += vs * h2[0]; a23 += vs * h2[1]; \
    a45 += vs * h2[2]; a67 += vs * h2[3]; }
    GATH(ca.x, vv[0]) GATH(ca.y, vv[1]) GATH(ca.z, vv[2]) GATH(ca.w, vv[3])
    GATH(cb.x, vv[4]) GATH(cb.y, vv[5]) GATH(cb.z, vv[6]) GATH(cb.w, vv[7])
#undef GATH
  }
  {
    int r0 = wv * 8;
    sdiff[(r0 + 0) * WS2 + lane] = a01[0];
    sdiff[(r0 + 1) * WS2 + lane] = a01[1];
    sdiff[(r0 + 2) * WS2 + lane] = a23[0];
    sdiff[(r0 + 3) * WS2 + lane] = a23[1];
    sdiff[(r0 + 4) * WS2 + lane] = a45[0];
    sdiff[(r0 + 5) * WS2 + lane] = a45[1];
    sdiff[(r0 + 6) * WS2 + lane] = a67[0];
    sdiff[(r0 + 7) * WS2 + lane] = a67[1];
  }
  __syncthreads();
  #pragma unroll
  for (int tt = 0; tt < 2; ++tt) {
    int rt = tt;                    // ot = wv
    f32x4 acc = {0.f, 0.f, 0.f, 0.f};
    #pragma unroll
    for (int s = 0; s < 2; ++s) {
      f16x8 bf = *(const f16x8*)&sdiff[(rt * 16 + l15) * WS2 + s * 32 + lq * 8];
      acc = __builtin_amdgcn_mfma_f32_16x16x32_f16(afrag[s], bf, acc, 0, 0, 0);
    }
    int R = rt * 16 + l15;
    int O = wv * 16 + lq * 4;
    *(f32x4*)&sC[R * CSB2 + O] = acc;
  }
  __syncthreads();
  float4 LxLo = *(const float4*)&LxT[(size_t)m * TB + t * BATCH];
  float4 LxHi = *(const float4*)&LxT[(size_t)m * TB + t * BATCH + 4];
  float Lx8[8] = {LxLo.x, LxLo.y, LxLo.z, LxLo.w,
                  LxHi.x, LxHi.y, LxHi.z, LxHi.w};
  float wxc = wcx[lane], bbc = bc[lane];
  float s[8];
  #pragma unroll
  for (int b = 0; b < 8; ++b) {
    int R = wv * 8 + b;
    s[b] = sC[R * CSB2 + lane] + fmaf(Lx8[b], wxc, bbc);
  }
  half8 hp = (statepk + lane)[m * 64];
  half8 uu = (upk + lane)[m * 64];
  half8 np;
  float* op = out + (size_t)t * BATCH * NH + m * HID + lane;
  #pragma unroll
  for (int b = 0; b < 8; ++b) {
    float u = (float)uu[b];
    float nh = u * (float)hp[b] + (1.f - u) * fast_tanh(s[b]);
    np[b] = (_Float16)nh;
    op[(size_t)b * NH] = nh;
  }
  (statepk_next + lane)[m * 64] = np;
}

extern "C" void kernel_launch(void* const* d_in, const int* in_sizes, int n_in,
                              void* d_out, int out_size, void* d_ws, size_t ws_size,
                              hipStream_t stream) {
  const float* x  = (const float*)d_in[0];
  const float* L  = (const float*)d_in[1];
  const float* Wg = (const float*)d_in[2];
  const float* bg = (const float*)d_in[3];
  const float* Wc = (const float*)d_in[4];
  const float* bc = (const float*)d_in[5];
  float* out = (float*)d_out;
  float* ws = (float*)d_ws;

  float*    ell_val  = ws;                                      // N*CAP f32
  int*      ell_colh = (int*)(ws + (size_t)N_NODES * CAP);      // N*CAP i32
  _Float16* ell_valh = (_Float16*)(ws + (size_t)2 * N_NODES * CAP); // N*CAP f16
  int*      ell_cnt  = (int*)(ws + (size_t)2 * N_NODES * CAP + N_NODES * CAP / 2); // N
  float* xT  = ws + (size_t)2 * N_NODES * CAP + N_NODES * CAP / 2 + N_NODES;
  float* LxT = xT + (size_t)N_NODES * TB;
  float* fend = LxT + (size_t)N_NODES * TB;
  half8* stA  = (half8*)fend;                                   // N*64 half8 = 2MB
  half8* stB  = stA + (size_t)N_NODES * HID;
  half8* rspk = stB + (size_t)N_NODES * HID;
  half8* upk  = rspk + (size_t)N_NODES * HID;
  _Float16* Wg16 = (_Float16*)(upk + (size_t)N_NODES * HID);    // 128*72 halves
  _Float16* Wc16 = Wg16 + 128 * WS2;                            // 64*72 halves
  float* wgx = (float*)(Wc16 + 64 * WS2);                       // 128 f32
  float* wcx = wgx + 128;                                       // 64 f32

  k_build_ell<<<N_NODES / 4, 256, 0, stream>>>(L, ell_val, ell_valh, ell_colh,
                                               ell_cnt);
  k_prep<<<64, 256, 0, stream>>>(Wg, Wc, Wg16, Wc16, wgx, wcx);
  k_xt<<<256, 256, 0, stream>>>(x, xT);
  k_spmm_x<<<N_NODES / 8, 512, 0, stream>>>(xT, ell_val, ell_colh, ell_cnt, LxT);
  hipMemsetAsync(stA, 0, (size_t)N_NODES * HID * sizeof(half8), stream);

  half8* cur = stA;
  half8* nxt = stB;
  for (int t = 0; t < SEQ; ++t) {
    k_gates<<<N_NODES / 4, 256, 0, stream>>>(cur, LxT, ell_valh, ell_colh,
                                             ell_cnt, Wg16, wgx, bg, rspk, upk,
                                             t);
    k_cand<<<N_NODES / 4, 256, 0, stream>>>(cur, LxT, ell_valh, ell_colh,
                                            ell_cnt, Wc16, wcx, bc, rspk, upk,
                                            nxt, out, t);
    half8* tmp = cur; cur = nxt; nxt = tmp;
  }
}